// Round 6
// baseline (203.150 us; speedup 1.0000x reference)
//
#include <hip/hip_runtime.h>
#include <hip/hip_bf16.h>
#include <stdint.h>
#include <stddef.h>

#define NVOX 262144
#define CCH 128
#define BN_EPS 1e-3f

typedef __attribute__((ext_vector_type(8))) short bfrag;   // 8 bf16 = 4 VGPRs
typedef __attribute__((ext_vector_type(4))) float f4;      // 4 f32

#define AS1 __attribute__((address_space(1)))
#define AS3 __attribute__((address_space(3)))

__device__ __forceinline__ unsigned short f2bf(float f) {
  union { float f; unsigned u; } v; v.f = f;
  unsigned r = v.u + 0x7fffu + ((v.u >> 16) & 1u);   // RNE (inputs finite)
  return (unsigned short)(r >> 16);
}

__device__ __forceinline__ bfrag pack8(f4 x, f4 y) {
  bfrag r;
  r[0] = (short)f2bf(x[0]); r[1] = (short)f2bf(x[1]);
  r[2] = (short)f2bf(x[2]); r[3] = (short)f2bf(x[3]);
  r[4] = (short)f2bf(y[0]); r[5] = (short)f2bf(y[1]);
  r[6] = (short)f2bf(y[2]); r[7] = (short)f2bf(y[3]);
  return r;
}

__device__ __forceinline__ float sigmoidf_(float x) {
  return 1.f / (1.f + __expf(-x));
}

__device__ __forceinline__ float bf2f(unsigned short h) {
  union { unsigned u; float f; } v; v.u = ((unsigned)h) << 16; return v.f;
}

// ---------------------------------------------------------------------------
// Pre-swizzle W1/W2/W3 into MFMA B-fragment order, bf16:
// region r = conv*3+tap (conv: 0=W1, 1=W2, 2=W3); frag = (r*4 + kc)*8 + tile
// lane holds B[k = kc*32 + (lane>>4)*8 + e][col = tile*16 + (lane&15)]
// ---------------------------------------------------------------------------
__global__ void prep_wfrag(const float* __restrict__ W1, const float* __restrict__ W2,
                           const float* __restrict__ W3, unsigned short* __restrict__ wf) {
  const int frag = blockIdx.x;           // 0..287
  const int tile = frag & 7;
  const int kc   = (frag >> 3) & 3;
  const int tap  = (frag >> 5) % 3;
  const int conv = frag / 96;
  const float* W = (conv == 0) ? W1 : ((conv == 1) ? W2 : W3);
  const int l   = threadIdx.x;           // 0..63
  const int col = tile * 16 + (l & 15);
  const int k0  = kc * 32 + (l >> 4) * 8;
  bfrag o;
#pragma unroll
  for (int e = 0; e < 8; ++e)
    o[e] = (short)f2bf(W[(size_t)(tap * CCH + k0 + e) * CCH + col]);
  *reinterpret_cast<bfrag*>(wf + (size_t)frag * 512 + l * 8) = o;
}

// ---------------------------------------------------------------------------
// BN scale/shift tables: bn[6][128] = {sc0, sh0, sc2, sh2, sc3, sh3}
// ---------------------------------------------------------------------------
__global__ void prep_bn(const float* g0, const float* b0, const float* m0, const float* v0,
                        const float* g2, const float* b2, const float* m2, const float* v2,
                        const float* g3, const float* b3, const float* m3, const float* v3,
                        float* __restrict__ bn) {
  const int c = threadIdx.x;
  const float s0 = g0[c] * rsqrtf(v0[c] + BN_EPS);
  const float s2 = g2[c] * rsqrtf(v2[c] + BN_EPS);
  const float s3 = g3[c] * rsqrtf(v3[c] + BN_EPS);
  bn[0 * CCH + c] = s0; bn[1 * CCH + c] = b0[c] - m0[c] * s0;
  bn[2 * CCH + c] = s2; bn[3 * CCH + c] = b2[c] - m2[c] * s2;
  bn[4 * CCH + c] = s3; bn[5 * CCH + c] = b3[c] - m3[c] * s3;
}

// ---------------------------------------------------------------------------
// Features fp32 -> bf16 (row N = zeros, the sentinel row)
// ---------------------------------------------------------------------------
__global__ void prep_bf16(const float* __restrict__ feats, unsigned short* __restrict__ fbf) {
  const size_t base = ((size_t)blockIdx.x * 256 + threadIdx.x) * 8;
  const f4 x = *reinterpret_cast<const f4*>(feats + base);
  const f4 y = *reinterpret_cast<const f4*>(feats + base + 4);
  *reinterpret_cast<bfrag*>(fbf + base) = pack8(x, y);
  if (blockIdx.x == 0 && threadIdx.x < 16) {
    bfrag z = {0, 0, 0, 0, 0, 0, 0, 0};
    *reinterpret_cast<bfrag*>(fbf + (size_t)NVOX * CCH + threadIdx.x * 8) = z;
  }
}

// ---------------------------------------------------------------------------
// v6: barrier-free main loop + 2 row-tiles/wave (B-fragment reuse).
// Block = 1024 threads = 16 waves; wave owns 32 rows x 64 cols; block covers
// 512 rows x 64-col half. All 9 B-tiles resident in 144 KB LDS (one fill +
// ONE barrier). A gathered directly into MFMA fragment registers (8 x 16B
// global loads per tap, one latency event, hidden by 4 waves/SIMD TLP).
// Each B ds_read_b128 feeds TWO MFMAs -> B LDS traffic halved vs v5.
// Slot order: conv-z(W1) 0-2, conv-x(W3) 3-5, conv-y(W2) 6-8 (y into run).
// ---------------------------------------------------------------------------
__global__ __launch_bounds__(1024, 4)
void recon_v6(const unsigned short* __restrict__ fbf,
              const unsigned short* __restrict__ wfrag,
              const float* __restrict__ bn,
              const int* __restrict__ nbrz, const int* __restrict__ nbrx,
              const int* __restrict__ nbry,
              float* __restrict__ out) {
  __shared__ unsigned short Bb[73728];   // 144 KB: 9 slots x 16 frags x 1 KB

  const int tid  = threadIdx.x;
  const int lane = tid & 63;
  const int w    = tid >> 6;        // wave 0..15
  const int l15  = lane & 15;
  const int lhi  = lane >> 4;       // 0..3
  const int cb   = blockIdx.x & 1;  // 64-col half
  const int row0 = (blockIdx.x >> 1) * 512;
  const int wrow = row0 + w * 32;

  // ---- B fill: wave w copies sub-frag (kc=w>>2, ct=w&3) of all 9 slots ----
  // slot i regions: 0-2 -> W1(z), 3-5 -> W3(x), 6-8 -> W2(y)
#pragma unroll
  for (int i = 0; i < 9; ++i) {
    const int r = (i < 3) ? i : ((i < 6) ? i + 3 : i - 3);
    const int g = (r * 4 + (w >> 2)) * 8 + cb * 4 + (w & 3);  // src frag
    __builtin_amdgcn_global_load_lds(
        (const AS1 void*)(wfrag + (size_t)g * 512 + lane * 8),
        (AS3 void*)((char*)Bb + (i * 16 + w) * 1024), 16, 0, 0);
  }

  // ---- neighbor indices: 2 row-tiles, lane-row = l15 ----
  int rowA, rowB, izp0, izp1, izn0, izn1, ixp0, ixp1, ixn0, ixn1, iyp0, iyp1, iyn0, iyn1;
  {
    rowA = wrow + l15;
    rowB = wrow + 16 + l15;
    const int ra = rowA * 3, rb = rowB * 3;
    izp0 = nbrz[ra]; izn0 = nbrz[ra + 2]; izp1 = nbrz[rb]; izn1 = nbrz[rb + 2];
    ixp0 = nbrx[ra]; ixn0 = nbrx[ra + 2]; ixp1 = nbrx[rb]; ixn1 = nbrx[rb + 2];
    iyp0 = nbry[ra]; iyn0 = nbry[ra + 2]; iyp1 = nbry[rb]; iyn1 = nbry[rb + 2];
  }

  asm volatile("s_waitcnt vmcnt(0)" ::: "memory");
  __syncthreads();   // the ONLY barrier

  f4 acc0[4], acc1[4], run0[4], run1[4];
#pragma unroll
  for (int ct = 0; ct < 4; ++ct) {
    acc0[ct] = f4{0.f, 0.f, 0.f, 0.f};
    acc1[ct] = f4{0.f, 0.f, 0.f, 0.f};
    run0[ct] = f4{0.f, 0.f, 0.f, 0.f};
    run1[ct] = f4{0.f, 0.f, 0.f, 0.f};
  }

  bfrag aX[4], aY[4];   // 32 VGPRs: A fragments for the two row-tiles

#define LOADA(I0, I1) {                                                       \
    const char* p0 = (const char*)fbf + ((size_t)(unsigned)(I0) << 8) + (lhi << 4); \
    const char* p1 = (const char*)fbf + ((size_t)(unsigned)(I1) << 8) + (lhi << 4); \
    aX[0] = *reinterpret_cast<const bfrag*>(p0);                              \
    aX[1] = *reinterpret_cast<const bfrag*>(p0 + 64);                         \
    aX[2] = *reinterpret_cast<const bfrag*>(p0 + 128);                        \
    aX[3] = *reinterpret_cast<const bfrag*>(p0 + 192);                        \
    aY[0] = *reinterpret_cast<const bfrag*>(p1);                              \
    aY[1] = *reinterpret_cast<const bfrag*>(p1 + 64);                         \
    aY[2] = *reinterpret_cast<const bfrag*>(p1 + 128);                        \
    aY[3] = *reinterpret_cast<const bfrag*>(p1 + 192);                        \
  }

#define TAP(SLOT, A0, A1) {                                                   \
    const char* bs = (const char*)Bb + (SLOT) * 16384 + lane * 16;            \
    _Pragma("unroll")                                                         \
    for (int kc = 0; kc < 4; ++kc) {                                          \
      _Pragma("unroll")                                                       \
      for (int ct = 0; ct < 4; ++ct) {                                        \
        const bfrag b = *reinterpret_cast<const bfrag*>(                      \
            bs + (kc * 4 + ct) * 1024);                                       \
        A0[ct] = __builtin_amdgcn_mfma_f32_16x16x32_bf16(aX[kc], b, A0[ct], 0, 0, 0); \
        A1[ct] = __builtin_amdgcn_mfma_f32_16x16x32_bf16(aY[kc], b, A1[ct], 0, 0, 0); \
      } } }

  // ---- conv-z (W1): prev, self, next ----
  LOADA(izp0, izp1)  TAP(0, acc0, acc1)
  LOADA(rowA, rowB)  TAP(1, acc0, acc1)
  LOADA(izn0, izn1)  TAP(2, acc0, acc1)
  // fold: run = sigmoid(bn2(sigmoid(bn0(acc)))); acc = 0
#pragma unroll
  for (int ct = 0; ct < 4; ++ct) {
    const int col = cb * 64 + ct * 16 + l15;
    const float sc0 = bn[0 * CCH + col], sh0 = bn[1 * CCH + col];
    const float sc2 = bn[2 * CCH + col], sh2 = bn[3 * CCH + col];
#pragma unroll
    for (int j = 0; j < 4; ++j) {
      const float u0 = sigmoidf_(sc0 * acc0[ct][j] + sh0);
      run0[ct][j] = sigmoidf_(sc2 * u0 + sh2);
      const float u1 = sigmoidf_(sc0 * acc1[ct][j] + sh0);
      run1[ct][j] = sigmoidf_(sc2 * u1 + sh2);
    }
    acc0[ct] = f4{0.f, 0.f, 0.f, 0.f};
    acc1[ct] = f4{0.f, 0.f, 0.f, 0.f};
  }
  // ---- conv-x (W3): prev, self, next ----
  LOADA(ixp0, ixp1)  TAP(3, acc0, acc1)
  LOADA(rowA, rowB)  TAP(4, acc0, acc1)
  LOADA(ixn0, ixn1)  TAP(5, acc0, acc1)
  // fold: run += sigmoid(bn3(acc))
#pragma unroll
  for (int ct = 0; ct < 4; ++ct) {
    const int col = cb * 64 + ct * 16 + l15;
    const float sc3 = bn[4 * CCH + col], sh3 = bn[5 * CCH + col];
#pragma unroll
    for (int j = 0; j < 4; ++j) {
      run0[ct][j] += sigmoidf_(sc3 * acc0[ct][j] + sh3);
      run1[ct][j] += sigmoidf_(sc3 * acc1[ct][j] + sh3);
    }
  }
  // ---- conv-y (W2): raw, MFMA directly into run ----
  LOADA(iyp0, iyp1)  TAP(6, run0, run1)
  LOADA(rowA, rowB)  TAP(7, run0, run1)
  LOADA(iyn0, iyn1)  TAP(8, run0, run1)

#undef TAP
#undef LOADA

  // ---- epilogue: multiply by features (bf16, cache-hot), store fp32 ----
#pragma unroll
  for (int ct = 0; ct < 4; ++ct) {
    const int col = cb * 64 + ct * 16 + l15;
#pragma unroll
    for (int j = 0; j < 4; ++j) {
      const int r0 = wrow + (lhi << 2) + j;
      const size_t o0 = ((size_t)r0 << 7) + col;
      out[o0] = run0[ct][j] * bf2f(fbf[o0]);
      const int r1 = wrow + 16 + (lhi << 2) + j;
      const size_t o1 = ((size_t)r1 << 7) + col;
      out[o1] = run1[ct][j] * bf2f(fbf[o1]);
    }
  }
}

// ---------------------------------------------------------------------------
// Last-resort fallback: exact fp32
// ---------------------------------------------------------------------------
__global__ void recon_naive(const float* __restrict__ feats,
    const float* __restrict__ W1, const float* __restrict__ W2, const float* __restrict__ W3,
    const int* __restrict__ nbrz, const int* __restrict__ nbry, const int* __restrict__ nbrx,
    const float* g0, const float* b0, const float* m0, const float* v0,
    const float* g2, const float* b2, const float* m2, const float* v2,
    const float* g3, const float* b3, const float* m3, const float* v3,
    float* __restrict__ out) {
  __shared__ float rows[3][CCH];
  const int n = blockIdx.x;
  const int d = threadIdx.x;
  float res[3];
#pragma unroll
  for (int conv = 0; conv < 3; ++conv) {
    const int* nbr  = (conv == 0) ? nbrz : ((conv == 1) ? nbry : nbrx);
    const float* W  = (conv == 0) ? W1 : ((conv == 1) ? W2 : W3);
#pragma unroll
    for (int tap = 0; tap < 3; ++tap) {
      const int idx = nbr[n * 3 + tap];
      rows[tap][d] = ((unsigned)idx < (unsigned)NVOX) ? feats[((size_t)idx << 7) + d] : 0.f;
    }
    __syncthreads();
    const float* rflat = &rows[0][0];
    float s = 0.f;
    for (int k = 0; k < 3 * CCH; ++k) s += rflat[k] * W[(size_t)k * CCH + d];
    res[conv] = s;
    __syncthreads();
  }
  const float sc0 = g0[d] * rsqrtf(v0[d] + BN_EPS), sh0 = b0[d] - m0[d] * sc0;
  const float sc2 = g2[d] * rsqrtf(v2[d] + BN_EPS), sh2 = b2[d] - m2[d] * sc2;
  const float sc3 = g3[d] * rsqrtf(v3[d] + BN_EPS), sh3 = b3[d] - m3[d] * sc3;
  float u = sigmoidf_(sc0 * res[0] + sh0);
  u = sigmoidf_(sc2 * u + sh2);
  const float s3v = sigmoidf_(sc3 * res[2] + sh3);
  out[((size_t)n << 7) + d] = (u + res[1] + s3v) * feats[((size_t)n << 7) + d];
}

extern "C" void kernel_launch(void* const* d_in, const int* in_sizes, int n_in,
                              void* d_out, int out_size, void* d_ws, size_t ws_size,
                              hipStream_t stream) {
  const float* feats = (const float*)d_in[0];
  const float* W1 = (const float*)d_in[1];
  const float* W2 = (const float*)d_in[2];
  const float* W3 = (const float*)d_in[3];
  const float* g0 = (const float*)d_in[4];
  const float* b0 = (const float*)d_in[5];
  const float* m0 = (const float*)d_in[6];
  const float* v0 = (const float*)d_in[7];
  const float* g2 = (const float*)d_in[8];
  const float* b2 = (const float*)d_in[9];
  const float* m2 = (const float*)d_in[10];
  const float* v2 = (const float*)d_in[11];
  const float* g3 = (const float*)d_in[12];
  const float* b3 = (const float*)d_in[13];
  const float* m3 = (const float*)d_in[14];
  const float* v3 = (const float*)d_in[15];
  const int* nz = (const int*)d_in[16];
  const int* ny = (const int*)d_in[17];
  const int* nx = (const int*)d_in[18];
  float* out = (float*)d_out;

  const size_t wf_bytes = 288u * 1024u;                              // 294912
  const size_t bn_bytes = 4096u;                                     // 6*128*4 padded
  const size_t fb_bytes = ((size_t)NVOX + 1) * CCH * sizeof(short);  // 67.1 MB
  if (ws_size >= wf_bytes + bn_bytes + fb_bytes) {
    unsigned short* wf  = (unsigned short*)d_ws;
    float*          bnt = (float*)((char*)d_ws + wf_bytes);
    unsigned short* fbf = (unsigned short*)((char*)d_ws + wf_bytes + bn_bytes);
    hipLaunchKernelGGL(prep_wfrag, dim3(288), dim3(64), 0, stream, W1, W2, W3, wf);
    hipLaunchKernelGGL(prep_bn, dim3(1), dim3(CCH), 0, stream,
                       g0, b0, m0, v0, g2, b2, m2, v2, g3, b3, m3, v3, bnt);
    hipLaunchKernelGGL(prep_bf16, dim3((NVOX * CCH) / (256 * 8)), dim3(256), 0, stream,
                       feats, fbf);
    hipLaunchKernelGGL(recon_v6, dim3((NVOX / 512) * 2), dim3(1024), 0, stream,
                       fbf, wf, bnt, nz, nx, ny, out);
  } else {
    hipLaunchKernelGGL(recon_naive, dim3(NVOX), dim3(CCH), 0, stream,
                       feats, W1, W2, W3, nz, ny, nx,
                       g0, b0, m0, v0, g2, b2, m2, v2, g3, b3, m3, v3, out);
  }
}

// Round 7
// 157.102 us; speedup vs baseline: 1.2931x; 1.2931x over previous
//
#include <hip/hip_runtime.h>
#include <hip/hip_bf16.h>
#include <stdint.h>
#include <stddef.h>

#define NVOX 262144
#define CCH 128
#define BN_EPS 1e-3f

typedef __attribute__((ext_vector_type(8))) short bfrag;   // 8 bf16 = 4 VGPRs
typedef __attribute__((ext_vector_type(4))) float f4;      // 4 f32

#define AS1 __attribute__((address_space(1)))
#define AS3 __attribute__((address_space(3)))

__device__ __forceinline__ unsigned short f2bf(float f) {
  union { float f; unsigned u; } v; v.f = f;
  unsigned r = v.u + 0x7fffu + ((v.u >> 16) & 1u);   // RNE (inputs finite)
  return (unsigned short)(r >> 16);
}

__device__ __forceinline__ bfrag pack8(f4 x, f4 y) {
  bfrag r;
  r[0] = (short)f2bf(x[0]); r[1] = (short)f2bf(x[1]);
  r[2] = (short)f2bf(x[2]); r[3] = (short)f2bf(x[3]);
  r[4] = (short)f2bf(y[0]); r[5] = (short)f2bf(y[1]);
  r[6] = (short)f2bf(y[2]); r[7] = (short)f2bf(y[3]);
  return r;
}

__device__ __forceinline__ float sigmoidf_(float x) {
  return 1.f / (1.f + __expf(-x));
}

__device__ __forceinline__ float bf2f(unsigned short h) {
  union { unsigned u; float f; } v; v.u = ((unsigned)h) << 16; return v.f;
}

// ---------------------------------------------------------------------------
// Pre-swizzle W1/W2/W3 into MFMA B-fragment order, bf16:
// region r = conv*3+tap (conv: 0=W1, 1=W2, 2=W3); frag = (r*4 + kc)*8 + tile
// lane holds B[k = kc*32 + (lane>>4)*8 + e][col = tile*16 + (lane&15)]
// ---------------------------------------------------------------------------
__global__ void prep_wfrag(const float* __restrict__ W1, const float* __restrict__ W2,
                           const float* __restrict__ W3, unsigned short* __restrict__ wf) {
  const int frag = blockIdx.x;           // 0..287
  const int tile = frag & 7;
  const int kc   = (frag >> 3) & 3;
  const int tap  = (frag >> 5) % 3;
  const int conv = frag / 96;
  const float* W = (conv == 0) ? W1 : ((conv == 1) ? W2 : W3);
  const int l   = threadIdx.x;           // 0..63
  const int col = tile * 16 + (l & 15);
  const int k0  = kc * 32 + (l >> 4) * 8;
  bfrag o;
#pragma unroll
  for (int e = 0; e < 8; ++e)
    o[e] = (short)f2bf(W[(size_t)(tap * CCH + k0 + e) * CCH + col]);
  *reinterpret_cast<bfrag*>(wf + (size_t)frag * 512 + l * 8) = o;
}

// ---------------------------------------------------------------------------
// BN scale/shift tables: bn[6][128] = {sc0, sh0, sc2, sh2, sc3, sh3}
// ---------------------------------------------------------------------------
__global__ void prep_bn(const float* g0, const float* b0, const float* m0, const float* v0,
                        const float* g2, const float* b2, const float* m2, const float* v2,
                        const float* g3, const float* b3, const float* m3, const float* v3,
                        float* __restrict__ bn) {
  const int c = threadIdx.x;
  const float s0 = g0[c] * rsqrtf(v0[c] + BN_EPS);
  const float s2 = g2[c] * rsqrtf(v2[c] + BN_EPS);
  const float s3 = g3[c] * rsqrtf(v3[c] + BN_EPS);
  bn[0 * CCH + c] = s0; bn[1 * CCH + c] = b0[c] - m0[c] * s0;
  bn[2 * CCH + c] = s2; bn[3 * CCH + c] = b2[c] - m2[c] * s2;
  bn[4 * CCH + c] = s3; bn[5 * CCH + c] = b3[c] - m3[c] * s3;
}

// ---------------------------------------------------------------------------
// Features fp32 -> bf16 (row N = zeros, the sentinel row)
// ---------------------------------------------------------------------------
__global__ void prep_bf16(const float* __restrict__ feats, unsigned short* __restrict__ fbf) {
  const size_t base = ((size_t)blockIdx.x * 256 + threadIdx.x) * 8;
  const f4 x = *reinterpret_cast<const f4*>(feats + base);
  const f4 y = *reinterpret_cast<const f4*>(feats + base + 4);
  *reinterpret_cast<bfrag*>(fbf + base) = pack8(x, y);
  if (blockIdx.x == 0 && threadIdx.x < 16) {
    bfrag z = {0, 0, 0, 0, 0, 0, 0, 0};
    *reinterpret_cast<bfrag*>(fbf + (size_t)NVOX * CCH + threadIdx.x * 8) = z;
  }
}

// ---------------------------------------------------------------------------
// v7 = v5 + sparsity skipping. Block = 1024 threads = 16 waves, wave owns
// 16 rows x 64 cols (block: 256 rows x 64-col half). All 9 B-tiles resident
// in 144 KB LDS, ONE barrier, waves fully async.
// NEW: off-center taps are skipped wave-uniformly when ALL 16 rows have the
// sentinel neighbor (P~82% per tap at 1.2% voxel density) -- bit-exact, since
// sentinel rows are zeros. Self-row A fragments hoisted and reused by the 3
// center taps. Expected executed taps/wave ~4.1 of 9.
// Slot order: conv-z(W1) 0-2, conv-x(W3) 3-5, conv-y(W2) 6-8 (y into run).
// ---------------------------------------------------------------------------
__global__ __launch_bounds__(1024, 4)
void recon_v7(const unsigned short* __restrict__ fbf,
              const unsigned short* __restrict__ wfrag,
              const float* __restrict__ bn,
              const int* __restrict__ nbrz, const int* __restrict__ nbrx,
              const int* __restrict__ nbry,
              float* __restrict__ out) {
  __shared__ unsigned short Bb[73728];   // 144 KB: 9 slots x 16 frags x 1 KB

  const int tid  = threadIdx.x;
  const int lane = tid & 63;
  const int w    = tid >> 6;        // wave 0..15
  const int l15  = lane & 15;
  const int lhi  = lane >> 4;       // 0..3
  const int cb   = blockIdx.x & 1;  // 64-col half
  const int row0 = (blockIdx.x >> 1) * 256;
  const int wrow = row0 + w * 16;

  // ---- B fill: wave w copies sub-frag (kc=w>>2, ct=w&3) of all 9 slots ----
  // slot i regions: 0-2 -> W1(z), 3-5 -> W3(x), 6-8 -> W2(y)
#pragma unroll
  for (int i = 0; i < 9; ++i) {
    const int r = (i < 3) ? i : ((i < 6) ? i + 3 : i - 3);
    const int g = (r * 4 + (w >> 2)) * 8 + cb * 4 + (w & 3);  // src frag
    __builtin_amdgcn_global_load_lds(
        (const AS1 void*)(wfrag + (size_t)g * 512 + lane * 8),
        (AS3 void*)((char*)Bb + (i * 16 + w) * 1024), 16, 0, 0);
  }
  // ---- neighbor indices for this lane's row (4-lane dup across lhi) ----
  const int row = wrow + l15;
  const int rg  = row * 3;
  const int izp = nbrz[rg + 0], izn = nbrz[rg + 2];
  const int ixp = nbrx[rg + 0], ixn = nbrx[rg + 2];
  const int iyp = nbry[rg + 0], iyn = nbry[rg + 2];

  asm volatile("s_waitcnt vmcnt(0)" ::: "memory");
  __syncthreads();   // the ONLY barrier

  f4 acc[4], run[4];
#pragma unroll
  for (int ct = 0; ct < 4; ++ct) {
    acc[ct] = f4{0.f, 0.f, 0.f, 0.f};
    run[ct] = f4{0.f, 0.f, 0.f, 0.f};
  }

  bfrag aF[4];   // gathered-neighbor fragments (reloaded per executed tap)
  bfrag aS[4];   // self-row fragments (loaded once, reused 3x)

  // wave-uniform validity of each off-center tap (any of the 16 rows valid)
  const bool azp = __any(izp != NVOX), azn = __any(izn != NVOX);
  const bool axp = __any(ixp != NVOX), axn = __any(ixn != NVOX);
  const bool ayp = __any(iyp != NVOX), ayn = __any(iyn != NVOX);

#define LOADF(DST, IDX) {                                                     \
    const char* p = (const char*)fbf + ((size_t)(unsigned)(IDX) << 8) + (lhi << 4); \
    DST[0] = *reinterpret_cast<const bfrag*>(p);                              \
    DST[1] = *reinterpret_cast<const bfrag*>(p + 64);                         \
    DST[2] = *reinterpret_cast<const bfrag*>(p + 128);                        \
    DST[3] = *reinterpret_cast<const bfrag*>(p + 192);                        \
  }

#define TAP(SLOT, AFR, ACCS) {                                                \
    const char* bs = (const char*)Bb + (SLOT) * 16384 + lane * 16;            \
    _Pragma("unroll")                                                         \
    for (int kc = 0; kc < 4; ++kc) {                                          \
      _Pragma("unroll")                                                       \
      for (int ct = 0; ct < 4; ++ct) {                                        \
        const bfrag b = *reinterpret_cast<const bfrag*>(                      \
            bs + (kc * 4 + ct) * 1024);                                       \
        ACCS[ct] = __builtin_amdgcn_mfma_f32_16x16x32_bf16(                   \
            AFR[kc], b, ACCS[ct], 0, 0, 0);                                   \
      } } }

  LOADF(aS, row)   // self row, reused by slots 1, 4, 7

  // ---- conv-z (W1): prev, self, next ----
  if (azp) { LOADF(aF, izp)  TAP(0, aF, acc) }
  TAP(1, aS, acc)
  if (azn) { LOADF(aF, izn)  TAP(2, aF, acc) }
  // fold: run = sigmoid(bn2(sigmoid(bn0(acc)))); acc = 0
#pragma unroll
  for (int ct = 0; ct < 4; ++ct) {
    const int col = cb * 64 + ct * 16 + l15;
    const float sc0 = bn[0 * CCH + col], sh0 = bn[1 * CCH + col];
    const float sc2 = bn[2 * CCH + col], sh2 = bn[3 * CCH + col];
#pragma unroll
    for (int j = 0; j < 4; ++j) {
      const float u = sigmoidf_(sc0 * acc[ct][j] + sh0);
      run[ct][j] = sigmoidf_(sc2 * u + sh2);
    }
    acc[ct] = f4{0.f, 0.f, 0.f, 0.f};
  }
  // ---- conv-x (W3): prev, self, next ----
  if (axp) { LOADF(aF, ixp)  TAP(3, aF, acc) }
  TAP(4, aS, acc)
  if (axn) { LOADF(aF, ixn)  TAP(5, aF, acc) }
  // fold: run += sigmoid(bn3(acc))
#pragma unroll
  for (int ct = 0; ct < 4; ++ct) {
    const int col = cb * 64 + ct * 16 + l15;
    const float sc3 = bn[4 * CCH + col], sh3 = bn[5 * CCH + col];
#pragma unroll
    for (int j = 0; j < 4; ++j)
      run[ct][j] += sigmoidf_(sc3 * acc[ct][j] + sh3);
  }
  // ---- conv-y (W2): raw, MFMA directly into run ----
  if (ayp) { LOADF(aF, iyp)  TAP(6, aF, run) }
  TAP(7, aS, run)
  if (ayn) { LOADF(aF, iyn)  TAP(8, aF, run) }

#undef TAP
#undef LOADF

  // ---- epilogue: multiply by features (bf16, cache-hot), store fp32 ----
#pragma unroll
  for (int ct = 0; ct < 4; ++ct) {
    const int col = cb * 64 + ct * 16 + l15;
#pragma unroll
    for (int j = 0; j < 4; ++j) {
      const int r = wrow + (lhi << 2) + j;
      const size_t o = ((size_t)r << 7) + col;
      out[o] = run[ct][j] * bf2f(fbf[o]);
    }
  }
}

// ---------------------------------------------------------------------------
// Last-resort fallback: exact fp32
// ---------------------------------------------------------------------------
__global__ void recon_naive(const float* __restrict__ feats,
    const float* __restrict__ W1, const float* __restrict__ W2, const float* __restrict__ W3,
    const int* __restrict__ nbrz, const int* __restrict__ nbry, const int* __restrict__ nbrx,
    const float* g0, const float* b0, const float* m0, const float* v0,
    const float* g2, const float* b2, const float* m2, const float* v2,
    const float* g3, const float* b3, const float* m3, const float* v3,
    float* __restrict__ out) {
  __shared__ float rows[3][CCH];
  const int n = blockIdx.x;
  const int d = threadIdx.x;
  float res[3];
#pragma unroll
  for (int conv = 0; conv < 3; ++conv) {
    const int* nbr  = (conv == 0) ? nbrz : ((conv == 1) ? nbry : nbrx);
    const float* W  = (conv == 0) ? W1 : ((conv == 1) ? W2 : W3);
#pragma unroll
    for (int tap = 0; tap < 3; ++tap) {
      const int idx = nbr[n * 3 + tap];
      rows[tap][d] = ((unsigned)idx < (unsigned)NVOX) ? feats[((size_t)idx << 7) + d] : 0.f;
    }
    __syncthreads();
    const float* rflat = &rows[0][0];
    float s = 0.f;
    for (int k = 0; k < 3 * CCH; ++k) s += rflat[k] * W[(size_t)k * CCH + d];
    res[conv] = s;
    __syncthreads();
  }
  const float sc0 = g0[d] * rsqrtf(v0[d] + BN_EPS), sh0 = b0[d] - m0[d] * sc0;
  const float sc2 = g2[d] * rsqrtf(v2[d] + BN_EPS), sh2 = b2[d] - m2[d] * sc2;
  const float sc3 = g3[d] * rsqrtf(v3[d] + BN_EPS), sh3 = b3[d] - m3[d] * sc3;
  float u = sigmoidf_(sc0 * res[0] + sh0);
  u = sigmoidf_(sc2 * u + sh2);
  const float s3v = sigmoidf_(sc3 * res[2] + sh3);
  out[((size_t)n << 7) + d] = (u + res[1] + s3v) * feats[((size_t)n << 7) + d];
}

extern "C" void kernel_launch(void* const* d_in, const int* in_sizes, int n_in,
                              void* d_out, int out_size, void* d_ws, size_t ws_size,
                              hipStream_t stream) {
  const float* feats = (const float*)d_in[0];
  const float* W1 = (const float*)d_in[1];
  const float* W2 = (const float*)d_in[2];
  const float* W3 = (const float*)d_in[3];
  const float* g0 = (const float*)d_in[4];
  const float* b0 = (const float*)d_in[5];
  const float* m0 = (const float*)d_in[6];
  const float* v0 = (const float*)d_in[7];
  const float* g2 = (const float*)d_in[8];
  const float* b2 = (const float*)d_in[9];
  const float* m2 = (const float*)d_in[10];
  const float* v2 = (const float*)d_in[11];
  const float* g3 = (const float*)d_in[12];
  const float* b3 = (const float*)d_in[13];
  const float* m3 = (const float*)d_in[14];
  const float* v3 = (const float*)d_in[15];
  const int* nz = (const int*)d_in[16];
  const int* ny = (const int*)d_in[17];
  const int* nx = (const int*)d_in[18];
  float* out = (float*)d_out;

  const size_t wf_bytes = 288u * 1024u;                              // 294912
  const size_t bn_bytes = 4096u;                                     // 6*128*4 padded
  const size_t fb_bytes = ((size_t)NVOX + 1) * CCH * sizeof(short);  // 67.1 MB
  if (ws_size >= wf_bytes + bn_bytes + fb_bytes) {
    unsigned short* wf  = (unsigned short*)d_ws;
    float*          bnt = (float*)((char*)d_ws + wf_bytes);
    unsigned short* fbf = (unsigned short*)((char*)d_ws + wf_bytes + bn_bytes);
    hipLaunchKernelGGL(prep_wfrag, dim3(288), dim3(64), 0, stream, W1, W2, W3, wf);
    hipLaunchKernelGGL(prep_bn, dim3(1), dim3(CCH), 0, stream,
                       g0, b0, m0, v0, g2, b2, m2, v2, g3, b3, m3, v3, bnt);
    hipLaunchKernelGGL(prep_bf16, dim3((NVOX * CCH) / (256 * 8)), dim3(256), 0, stream,
                       feats, fbf);
    hipLaunchKernelGGL(recon_v7, dim3((NVOX / 256) * 2), dim3(1024), 0, stream,
                       fbf, wf, bnt, nz, nx, ny, out);
  } else {
    hipLaunchKernelGGL(recon_naive, dim3(NVOX), dim3(CCH), 0, stream,
                       feats, W1, W2, W3, nz, ny, nx,
                       g0, b0, m0, v0, g2, b2, m2, v2, g3, b3, m3, v3, out);
  }
}